// Round 7
// baseline (3015.446 us; speedup 1.0000x reference)
//
#include <hip/hip_runtime.h>
#include <math.h>

#define TBB 32
#define CC  256
#define NN  196
#define NJ  (TBB * NN)            // 6272
#define HD  1024
#define SLAB   ((size_t)TBB * CC * NN)   // 1,605,632
#define SLAB1K ((size_t)TBB * HD * NN)   // 6,422,528

struct Ptr6  { const float* p[6]; };
struct PtrM6 { float*       p[6]; };

struct GArg {
    const float* W;  const float* In;
    const float* W2; const float* In2;
    const float* bias; const float* bias2;
    float* Z;
};
struct GArgs { GArg a[6]; };

// async global->LDS, 16B per lane, LDS dest = wave-uniform base + lane*16
__device__ __forceinline__ void async_copy16(const float* gsrc, float* ldst)
{
    typedef __attribute__((address_space(1))) void GV;
    typedef __attribute__((address_space(3))) void LV;
    __builtin_amdgcn_global_load_lds((GV*)const_cast<float*>(gsrc), (LV*)ldst,
                                     16, 0, 0);
}

// ---------------------------------------------------------------------------
// GEMM: Z[m, d, n] = sum_c W[d,c] * In[m, c, n]  (optional pass 2 with W2/In2
// continuing the SAME accumulator chain; optional bias/bias2 added last).
// 64x64 tile, 128 threads (2 waves), 4x8 micro-tile, K-tile 16,
// double-buffered LDS, B staged via global_load_lds dwordx4.
// __launch_bounds__(128, 4): cap VGPR at 128 -> 16 waves/CU (round 2 was 132
// VGPR -> 8 waves/CU -> regression; the 4x8 LDS/VALU ratio itself is good).
// Per-output FMA order (kt asc, kk asc, pass0 then pass1, bias last) is
// BIT-IDENTICAL to the round-1 kernel -> all spikes unchanged (verified in
// round 2: absmax 0.0).
// mode 0: write z (+bias).  mode 1: write LIF spike (z >= 1).
// ---------------------------------------------------------------------------
__global__ __launch_bounds__(128, 4) void gemm3(GArgs ga, int Cout, int Cin, int mode)
{
    __shared__ __align__(16) float As[2][16][68];   // K-major, padded (2-way max on writes)
    __shared__ __align__(16) float Bs[2][16][64];   // linear: async-copy target

    const GArg g = ga.a[blockIdx.z];
    const int t  = threadIdx.x;
    const int tx = t & 7;            // j-thread 0..7
    const int ty = t >> 3;           // d-thread 0..15
    const int d0 = blockIdx.x * 64;
    const int j0 = blockIdx.y * 64;
    const int wave = t >> 6;

    // B staging: 2 cluster-insts per K-tile; thread covers row 8q + (t>>4),
    // cols (t&15)*4 .. +3  (contiguous & 16B-aligned: 196 % 4 == 0).
    const int brow = t >> 4;                   // 0..7
    const int bj   = j0 + (t & 15) * 4;
    const int bm   = bj / NN;
    const int bn   = bj - bm * NN;
    // A staging: thread covers W row t>>1, two float4 at K offsets wk0, wk0+4
    const int wrow = t >> 1;                   // 0..63
    const int wk0  = (t & 1) * 8;              // 0 or 8

    float acc[4][8] = {{0.f}};
    float4 wa, wb;

    for (int pass = 0; pass < 2; ++pass) {
        const float* Wp = pass ? g.W2 : g.W;
        const float* Ip = pass ? g.In2 : g.In;
        if (Wp == nullptr) break;
        const int nkt = Cin >> 4;
        const size_t wbase = (size_t)(d0 + wrow) * Cin + wk0;
        const size_t bbase = (size_t)bm * Cin * NN + bn;

        // prologue: stage K-tile 0 into buffer 0
        async_copy16(Ip + bbase + (size_t)brow * NN,       &Bs[0][4 * wave][0]);
        async_copy16(Ip + bbase + (size_t)(8 + brow) * NN, &Bs[0][8 + 4 * wave][0]);
        wa = *(const float4*)(Wp + wbase);
        wb = *(const float4*)(Wp + wbase + 4);
        As[0][wk0 + 0][wrow] = wa.x; As[0][wk0 + 1][wrow] = wa.y;
        As[0][wk0 + 2][wrow] = wa.z; As[0][wk0 + 3][wrow] = wa.w;
        As[0][wk0 + 4][wrow] = wb.x; As[0][wk0 + 5][wrow] = wb.y;
        As[0][wk0 + 6][wrow] = wb.z; As[0][wk0 + 7][wrow] = wb.w;
        __syncthreads();

        for (int kt = 0; kt < nkt; ++kt) {
            const int  cur  = kt & 1;
            const int  nxt  = cur ^ 1;
            const bool more = (kt + 1) < nkt;
            if (more) {
                const int k0n = (kt + 1) << 4;
                async_copy16(Ip + bbase + (size_t)(k0n + brow) * NN,
                             &Bs[nxt][4 * wave][0]);
                async_copy16(Ip + bbase + (size_t)(k0n + 8 + brow) * NN,
                             &Bs[nxt][8 + 4 * wave][0]);
                wa = *(const float4*)(Wp + wbase + k0n);
                wb = *(const float4*)(Wp + wbase + k0n + 4);
            }
            #pragma unroll
            for (int kk = 0; kk < 16; ++kk) {
                const float4 a4 = *(const float4*)(&As[cur][kk][ty * 4]);
                const float4 b0 = *(const float4*)(&Bs[cur][kk][tx * 4]);
                const float4 b1 = *(const float4*)(&Bs[cur][kk][32 + tx * 4]);
                const float ar[4] = {a4.x, a4.y, a4.z, a4.w};
                const float br[8] = {b0.x, b0.y, b0.z, b0.w,
                                     b1.x, b1.y, b1.z, b1.w};
                #pragma unroll
                for (int i = 0; i < 4; ++i)
                    #pragma unroll
                    for (int jj = 0; jj < 8; ++jj)
                        acc[i][jj] = fmaf(ar[i], br[jj], acc[i][jj]);
            }
            if (more) {
                As[nxt][wk0 + 0][wrow] = wa.x; As[nxt][wk0 + 1][wrow] = wa.y;
                As[nxt][wk0 + 2][wrow] = wa.z; As[nxt][wk0 + 3][wrow] = wa.w;
                As[nxt][wk0 + 4][wrow] = wb.x; As[nxt][wk0 + 5][wrow] = wb.y;
                As[nxt][wk0 + 6][wrow] = wb.z; As[nxt][wk0 + 7][wrow] = wb.w;
            }
            __syncthreads();
        }
    }

    // epilogue: float4 stores (4 j's contiguous in n, 16B-aligned)
    #pragma unroll
    for (int i = 0; i < 4; ++i) {
        const int d = d0 + ty * 4 + i;
        float bv = 0.f;
        if (g.bias)  bv += g.bias[d];
        if (g.bias2) bv += g.bias2[d];
        #pragma unroll
        for (int jh = 0; jh < 2; ++jh) {
            const int j = j0 + jh * 32 + tx * 4;
            const int m = j / NN;
            const int n = j - m * NN;
            float4 o;
            const float v0 = acc[i][jh * 4 + 0] + bv;
            const float v1 = acc[i][jh * 4 + 1] + bv;
            const float v2 = acc[i][jh * 4 + 2] + bv;
            const float v3 = acc[i][jh * 4 + 3] + bv;
            if (mode == 1) {
                o.x = (v0 >= 1.f) ? 1.f : 0.f;
                o.y = (v1 >= 1.f) ? 1.f : 0.f;
                o.z = (v2 >= 1.f) ? 1.f : 0.f;
                o.w = (v3 >= 1.f) ? 1.f : 0.f;
            } else {
                o.x = v0; o.y = v1; o.z = v2; o.w = v3;
            }
            *(float4*)(g.Z + (size_t)(m * Cout + d) * NN + n) = o;
        }
    }
}

// ---------------------------------------------------------------------------
// BN stats: per channel d, over (m, n). fp64 accumulation (unchanged numerics).
// grid (Cout, nconv)
// ---------------------------------------------------------------------------
__global__ __launch_bounds__(256) void bn_stats(
    Ptr6 Zs, Ptr6 gs, Ptr6 bs, int Cout,
    float* __restrict__ scale, float* __restrict__ shift)
{
    const int d = blockIdx.x, g = blockIdx.y, t = threadIdx.x;
    const float* Z = Zs.p[g];
    double s = 0.0, s2 = 0.0;
    for (int i = t; i < NJ; i += 256) {
        int m = i / NN, n = i - m * NN;
        double v = (double)Z[(size_t)(m * Cout + d) * NN + n];
        s += v; s2 += v * v;
    }
    __shared__ double sh[256], sh2[256];
    sh[t] = s; sh2[t] = s2;
    __syncthreads();
    for (int off = 128; off > 0; off >>= 1) {
        if (t < off) { sh[t] += sh[t + off]; sh2[t] += sh2[t + off]; }
        __syncthreads();
    }
    if (t == 0) {
        double mu  = sh[0] / (double)NJ;
        double var = sh2[0] / (double)NJ - mu * mu;
        double a   = (double)gs.p[g][d] / sqrt(var + 1e-5);
        scale[g * Cout + d] = (float)a;
        shift[g * Cout + d] = (float)((double)bs.p[g][d] - mu * a);
    }
}

// spike = (scale[d]*z + shift[d] >= 1); mode 1: out = spike + Rs (residual add)
// float4-vectorized. grid (total4/256, nconv)
__global__ __launch_bounds__(256) void bn_apply2(
    Ptr6 Zs, PtrM6 Ss, Ptr6 Rs, const float* __restrict__ scale,
    const float* __restrict__ shift, int Cout, int total4, int mode)
{
    const int gix = blockIdx.y;
    const int i4  = blockIdx.x * 256 + threadIdx.x;
    if (i4 >= total4) return;
    const size_t base = (size_t)i4 * 4;
    const int d = (int)((base / NN) % (size_t)Cout);   // 4 elems share one d
    const float sc = scale[gix * Cout + d];
    const float sh = shift[gix * Cout + d];
    const float4 z = *(const float4*)(Zs.p[gix] + base);
    float4 o;
    o.x = (fmaf(sc, z.x, sh) >= 1.f) ? 1.f : 0.f;
    o.y = (fmaf(sc, z.y, sh) >= 1.f) ? 1.f : 0.f;
    o.z = (fmaf(sc, z.z, sh) >= 1.f) ? 1.f : 0.f;
    o.w = (fmaf(sc, z.w, sh) >= 1.f) ? 1.f : 0.f;
    if (mode == 1) {
        const float4 r = *(const float4*)(Rs.p[gix] + base);
        o.x += r.x; o.y += r.y; o.z += r.z; o.w += r.w;
    }
    *(float4*)(Ss.p[gix] + base) = o;
}

// ---------------------------------------------------------------------------
// Attention body (exact bit-packed popcount) — identical math to rounds 0-6.
// ---------------------------------------------------------------------------
__device__ __forceinline__ void attention_body(
    const float* __restrict__ Q, const float* __restrict__ K,
    const float* __restrict__ V, const float* __restrict__ P,
    float* __restrict__ O, int m, int h, int t,
    unsigned int* qb, unsigned int* kb, unsigned int* vb, float* Pl)
{
    if (P) { for (int i = t; i < 841; i += 256) Pl[i] = P[i]; }
    if (t < 196) {
        unsigned int q = 0, k = 0, v = 0;
        size_t base = (size_t)m * CC * NN + (size_t)h * 16 * NN + t;
        #pragma unroll
        for (int dd = 0; dd < 16; ++dd) {
            size_t off = base + (size_t)dd * NN;
            if (Q[off] > 0.5f) q |= (1u << dd);
            if (K[off] > 0.5f) k |= (1u << dd);
            if (V[off] > 0.5f) v |= (1u << dd);
        }
        qb[t] = q; kb[t] = k; vb[t] = v;
    }
    __syncthreads();

    if (t < 196) {
        int acc[16] = {0};
        const int ni = t / 14, nj = t - ni * 14;
        const unsigned int qr = qb[t];
        if (P) {
            for (int mm = 0; mm < 196; ++mm) {
                int a = __popc(qr & kb[mm]);
                int mi = mm / 14, mj = mm - mi * 14;
                float sv = (float)a + Pl[(ni - mi + 14) * 29 + (nj - mj + 14)];
                if (sv >= 1.f) {
                    unsigned int vv = vb[mm];
                    #pragma unroll
                    for (int dd = 0; dd < 16; ++dd)
                        acc[dd] += (vv >> dd) & 1;
                }
            }
        } else {
            for (int mm = 0; mm < 196; ++mm) {
                int a = __popc(qr & kb[mm]);
                if (a) {
                    unsigned int vv = vb[mm];
                    #pragma unroll
                    for (int dd = 0; dd < 16; ++dd)
                        acc[dd] += ((vv >> dd) & 1) ? a : 0;
                }
            }
        }
        size_t base = (size_t)m * CC * NN + (size_t)h * 16 * NN + t;
        #pragma unroll
        for (int dd = 0; dd < 16; ++dd)
            O[base + (size_t)dd * NN] = (acc[dd] >= 2) ? 1.f : 0.f;  // 0.25*acc >= 0.5
    }
}

// Both attention branches in one launch: z=0 -> x-branch (no rpb),
// z=1 -> y-branch (with rpb). grid (32, 16, 2).
__global__ __launch_bounds__(256) void attention_k2(
    const float* __restrict__ Q0, const float* __restrict__ K0,
    const float* __restrict__ V0, float* __restrict__ O0,
    const float* __restrict__ Q1, const float* __restrict__ K1,
    const float* __restrict__ V1, float* __restrict__ O1,
    const float* __restrict__ P)
{
    __shared__ unsigned int qb[196], kb[196], vb[196];
    __shared__ float Pl[841];
    const int m = blockIdx.x, h = blockIdx.y, t = threadIdx.x;
    if (blockIdx.z == 0)
        attention_body(Q0, K0, V0, nullptr, O0, m, h, t, qb, kb, vb, Pl);
    else
        attention_body(Q1, K1, V1, P,       O1, m, h, t, qb, kb, vb, Pl);
}

extern "C" void kernel_launch(void* const* d_in, const int* in_sizes, int n_in,
                              void* d_out, int out_size, void* d_ws, size_t ws_size,
                              hipStream_t stream)
{
    const float* x     = (const float*)d_in[0];
    const float* y     = (const float*)d_in[1];
    const float* av_w  = (const float*)d_in[2];
    const float* av_g  = (const float*)d_in[3];
    const float* av_b  = (const float*)d_in[4];
    const float* va_w  = (const float*)d_in[5];
    const float* va_g  = (const float*)d_in[6];
    const float* va_b  = (const float*)d_in[7];
    const float* P_rpb = (const float*)d_in[8];
    const float* fc1_w = (const float*)d_in[9];
    const float* fc1_b = (const float*)d_in[10];
    const float* fc2_w = (const float*)d_in[11];
    const float* fc2_b = (const float*)d_in[12];
    const float* m1_w  = (const float*)d_in[13];
    const float* m1_b  = (const float*)d_in[14];
    const float* m1_g  = (const float*)d_in[15];
    const float* m1_bb = (const float*)d_in[16];
    const float* m2_w  = (const float*)d_in[17];
    const float* m2_b  = (const float*)d_in[18];
    const float* m2_g  = (const float*)d_in[19];
    const float* m2_bb = (const float*)d_in[20];
    float* out = (float*)d_out;

    float* ws    = (float*)d_ws;
    float* A     = ws;               // 6 * SLAB
    float* Bf    = A  + 6 * SLAB;    // 2 * SLAB
    float* Cf    = Bf + 2 * SLAB;    // 2 * SLAB
    float* scale = Cf + 2 * SLAB;    // 6 * 1024
    float* shift = scale + 6 * 1024;

    const size_t CC2 = (size_t)CC * CC;
    const int apply256  = (int)(SLAB / 4 / 256);     // 1568
    const int apply1024 = (int)(SLAB1K / 4 / 256);   // 6272

    // ---- Stage A: 6 first-layer convs (batched) -> A slabs --------------
    GArgs ga{};
    {
        const float* Wl[6] = { av_w, av_w + CC2, av_w + 2*CC2, va_w, va_w + CC2, va_w + 2*CC2 };
        const float* Il[6] = { x, y, y, y, x, x };
        for (int i = 0; i < 6; ++i)
            ga.a[i] = GArg{ Wl[i], Il[i], nullptr, nullptr, nullptr, nullptr, A + i*SLAB };
    }
    gemm3<<<dim3(CC/64, NJ/64, 6), 128, 0, stream>>>(ga, CC, CC, 0);

    Ptr6 Zs{}, gs{}, bs{}, Rs{}; PtrM6 Ss{};
    {
        const float* gl[6] = { av_g, av_g + CC, av_g + 2*CC, va_g, va_g + CC, va_g + 2*CC };
        const float* bl[6] = { av_b, av_b + CC, av_b + 2*CC, va_b, va_b + CC, va_b + 2*CC };
        for (int i = 0; i < 6; ++i) {
            Zs.p[i] = A + i*SLAB; Ss.p[i] = A + i*SLAB; gs.p[i] = gl[i]; bs.p[i] = bl[i];
        }
    }
    bn_stats<<<dim3(CC, 6), 256, 0, stream>>>(Zs, gs, bs, CC, scale, shift);
    bn_apply2<<<dim3(apply256, 6), 256, 0, stream>>>(Zs, Ss, Rs, scale, shift, CC, (int)(SLAB/4), 0);

    // ---- Stage B: both attentions, one launch ---------------------------
    attention_k2<<<dim3(TBB, 16, 2), 256, 0, stream>>>(
        A, A + SLAB, A + 2*SLAB, Bf,
        A + 3*SLAB, A + 4*SLAB, A + 5*SLAB, Bf + SLAB, P_rpb);

    // ---- Stage C: W3 conv (batched x2) + BN + LIF + residual -> x1,y1 ---
    GArgs gc{};
    gc.a[0] = GArg{ av_w + 3*CC2, Bf,        nullptr, nullptr, nullptr, nullptr, Cf };
    gc.a[1] = GArg{ va_w + 3*CC2, Bf + SLAB, nullptr, nullptr, nullptr, nullptr, Cf + SLAB };
    gemm3<<<dim3(CC/64, NJ/64, 2), 128, 0, stream>>>(gc, CC, CC, 0);
    Zs.p[0] = Cf; Zs.p[1] = Cf + SLAB;
    gs.p[0] = av_g + 3*CC; gs.p[1] = va_g + 3*CC;
    bs.p[0] = av_b + 3*CC; bs.p[1] = va_b + 3*CC;
    Rs.p[0] = x; Rs.p[1] = y;
    Ss.p[0] = A; Ss.p[1] = A + SLAB;          // x1, y1
    bn_stats<<<dim3(CC, 2), 256, 0, stream>>>(Zs, gs, bs, CC, scale, shift);
    bn_apply2<<<dim3(apply256, 2), 256, 0, stream>>>(Zs, Ss, Rs, scale, shift, CC, (int)(SLAB/4), 1);

    // ---- fc1@x1 + fc2@y1 + biases, fused LIF -> cur (Bf+SLAB) ----------
    GArgs gf{};
    gf.a[0] = GArg{ fc1_w, A, fc2_w, A + SLAB, fc1_b, fc2_b, Bf + SLAB };
    gemm3<<<dim3(CC/64, NJ/64, 1), 128, 0, stream>>>(gf, CC, CC, 1);

    // ---- m1: (1024x256) @ cur + BN + LIF -> h in A ---------------------
    GArgs g1{};
    g1.a[0] = GArg{ m1_w, Bf + SLAB, nullptr, nullptr, m1_b, nullptr, A };
    gemm3<<<dim3(HD/64, NJ/64, 1), 128, 0, stream>>>(g1, HD, CC, 0);
    Zs.p[0] = A; Ss.p[0] = A; gs.p[0] = m1_g; bs.p[0] = m1_bb;
    bn_stats<<<dim3(HD, 1), 256, 0, stream>>>(Zs, gs, bs, HD, scale, shift);
    bn_apply2<<<dim3(apply1024, 1), 256, 0, stream>>>(Zs, Ss, Rs, scale, shift, HD, (int)(SLAB1K/4), 0);

    // ---- m2: (256x1024) @ h + BN + LIF + (cur +) -> out ----------------
    GArgs g2{};
    g2.a[0] = GArg{ m2_w, A, nullptr, nullptr, m2_b, nullptr, Cf };
    gemm3<<<dim3(CC/64, NJ/64, 1), 128, 0, stream>>>(g2, CC, HD, 0);
    Zs.p[0] = Cf; gs.p[0] = m2_g; bs.p[0] = m2_bb;
    Rs.p[0] = Bf + SLAB;                      // cur
    Ss.p[0] = out;                            // out = cur + o  (fused)
    bn_stats<<<dim3(CC, 1), 256, 0, stream>>>(Zs, gs, bs, CC, scale, shift);
    bn_apply2<<<dim3(apply256, 1), 256, 0, stream>>>(Zs, Ss, Rs, scale, shift, CC, (int)(SLAB/4), 1);
}

// Round 8
// 662.495 us; speedup vs baseline: 4.5517x; 4.5517x over previous
//
#include <hip/hip_runtime.h>
#include <math.h>

#define TBB 32
#define CC  256
#define NN  196
#define NJ  (TBB * NN)            // 6272
#define HD  1024
#define SLAB   ((size_t)TBB * CC * NN)   // 1,605,632
#define SLAB1K ((size_t)TBB * HD * NN)   // 6,422,528

struct Ptr6  { const float* p[6]; };
struct PtrM6 { float*       p[6]; };

struct GArg {
    const float* W;  const float* In;
    const float* W2; const float* In2;
    const float* bias; const float* bias2;
    float* Z;
};
struct GArgs { GArg a[6]; };

// async global->LDS, 16B per lane, LDS dest = wave-uniform base + lane*16
__device__ __forceinline__ void async_copy16(const float* gsrc, float* ldst)
{
    typedef __attribute__((address_space(1))) void GV;
    typedef __attribute__((address_space(3))) void LV;
    __builtin_amdgcn_global_load_lds((GV*)const_cast<float*>(gsrc), (LV*)ldst,
                                     16, 0, 0);
}

// ---------------------------------------------------------------------------
// GEMM: Z[m, d, n] = sum_c W[d,c] * In[m, c, n]  (optional pass 2 with W2/In2
// continuing the SAME accumulator chain; optional bias/bias2 added last).
// 128(d) x 64(j) tile, 256 threads, 8x4 micro-tile, K-tile 16.
// KEY CHANGE vs round-1 gemm2: A (weights) bypasses LDS entirely — each
// thread loads its 8 W-rows as float4 from global (L1/L2-resident, 16-lane
// coalesced) into registers, per 4-kk group. LDS now carries ONLY B:
// 1 ds_read_b128 per kk per wave -> LDS-unit demand (4 waves x 12cy = 48cy)
// drops below VALU demand (32 FMA x 2cy = 64cy) -> VALU-bound (was 2 reads,
// 96cy vs 64 -> LDS-bound at ~43% VALUBusy).
// Per-output FMA order is k ascending 0..Cin-1 — BIT-IDENTICAL to round 1.
// mode 0: write z (+bias). mode 1: write LIF spike (z >= 1).
// ---------------------------------------------------------------------------
__global__ __launch_bounds__(256) void gemm4(GArgs ga, int Cout, int Cin, int mode)
{
    __shared__ __align__(16) float Bs[2][16][64];   // B only; async-copy target

    const GArg g = ga.a[blockIdx.z];
    const int t  = threadIdx.x;
    const int tx = t & 15;           // j-quad 0..15
    const int ty = t >> 4;           // d-octet 0..15
    const int d0 = blockIdx.x * 128;
    const int j0 = blockIdx.y * 64;
    const int lane = t & 63, wave = t >> 6;

    // B staging (identical to round-1): 256 threads cover [16][64] per K-tile
    const int brow = wave * 4 + (lane >> 4);   // K row 0..15
    const int bj   = j0 + (lane & 15) * 4;
    const int bm   = bj / NN;
    const int bn   = bj - bm * NN;
    float* bdst0 = &Bs[0][wave * 4][0];
    float* bdst1 = &Bs[1][wave * 4][0];

    float acc[8][4] = {{0.f}};

    for (int pass = 0; pass < 2; ++pass) {
        const float* Wp = pass ? g.W2 : g.W;
        const float* Ip = pass ? g.In2 : g.In;
        if (Wp == nullptr) break;
        const int nkt = Cin >> 4;
        const size_t bbase = (size_t)bm * Cin * NN + bn;
        const float* wp0 = Wp + (size_t)(d0 + ty * 8) * Cin;  // thread's 8 W rows

        // prologue: stage B K-tile 0 into buffer 0
        async_copy16(Ip + bbase + (size_t)brow * NN, bdst0);
        __syncthreads();

        for (int kt = 0; kt < nkt; ++kt) {
            const int  cur  = kt & 1;
            const bool more = (kt + 1) < nkt;
            if (more)
                async_copy16(Ip + bbase + (size_t)((kt + 1) * 16 + brow) * NN,
                             (cur ^ 1) ? bdst1 : bdst0);
            const int k0 = kt << 4;
            #pragma unroll
            for (int kg = 0; kg < 4; ++kg) {
                // A: 8 rows x 4 k's from global (L1-hit), registers only
                float4 aw[8];
                #pragma unroll
                for (int i = 0; i < 8; ++i)
                    aw[i] = *(const float4*)(wp0 + (size_t)i * Cin + (k0 + kg * 4));
                #pragma unroll
                for (int kk2 = 0; kk2 < 4; ++kk2) {
                    const float4 b4 = *(const float4*)(&Bs[cur][kg * 4 + kk2][tx * 4]);
                    const float br[4] = {b4.x, b4.y, b4.z, b4.w};
                    #pragma unroll
                    for (int i = 0; i < 8; ++i) {
                        const float a = (kk2 == 0) ? aw[i].x :
                                        (kk2 == 1) ? aw[i].y :
                                        (kk2 == 2) ? aw[i].z : aw[i].w;
                        #pragma unroll
                        for (int jj = 0; jj < 4; ++jj)
                            acc[i][jj] = fmaf(a, br[jj], acc[i][jj]);
                    }
                }
            }
            __syncthreads();
        }
    }

    // epilogue: float4 stores (j-quad contiguous in n, 16B-aligned)
    {
        const int j = j0 + tx * 4;
        const int m = j / NN;
        const int n = j - m * NN;
        #pragma unroll
        for (int i = 0; i < 8; ++i) {
            const int d = d0 + ty * 8 + i;
            float bv = 0.f;
            if (g.bias)  bv += g.bias[d];
            if (g.bias2) bv += g.bias2[d];
            float4 o;
            const float v0 = acc[i][0] + bv;
            const float v1 = acc[i][1] + bv;
            const float v2 = acc[i][2] + bv;
            const float v3 = acc[i][3] + bv;
            if (mode == 1) {
                o.x = (v0 >= 1.f) ? 1.f : 0.f;
                o.y = (v1 >= 1.f) ? 1.f : 0.f;
                o.z = (v2 >= 1.f) ? 1.f : 0.f;
                o.w = (v3 >= 1.f) ? 1.f : 0.f;
            } else {
                o.x = v0; o.y = v1; o.z = v2; o.w = v3;
            }
            *(float4*)(g.Z + (size_t)(m * Cout + d) * NN + n) = o;
        }
    }
}

// ---------------------------------------------------------------------------
// BN stats: per channel d, over (m, n). fp64 accumulation (unchanged numerics).
// grid (Cout, nconv)
// ---------------------------------------------------------------------------
__global__ __launch_bounds__(256) void bn_stats(
    Ptr6 Zs, Ptr6 gs, Ptr6 bs, int Cout,
    float* __restrict__ scale, float* __restrict__ shift)
{
    const int d = blockIdx.x, g = blockIdx.y, t = threadIdx.x;
    const float* Z = Zs.p[g];
    double s = 0.0, s2 = 0.0;
    for (int i = t; i < NJ; i += 256) {
        int m = i / NN, n = i - m * NN;
        double v = (double)Z[(size_t)(m * Cout + d) * NN + n];
        s += v; s2 += v * v;
    }
    __shared__ double sh[256], sh2[256];
    sh[t] = s; sh2[t] = s2;
    __syncthreads();
    for (int off = 128; off > 0; off >>= 1) {
        if (t < off) { sh[t] += sh[t + off]; sh2[t] += sh2[t + off]; }
        __syncthreads();
    }
    if (t == 0) {
        double mu  = sh[0] / (double)NJ;
        double var = sh2[0] / (double)NJ - mu * mu;
        double a   = (double)gs.p[g][d] / sqrt(var + 1e-5);
        scale[g * Cout + d] = (float)a;
        shift[g * Cout + d] = (float)((double)bs.p[g][d] - mu * a);
    }
}

// spike = (scale[d]*z + shift[d] >= 1); mode 1: out = spike + Rs (residual add)
// float4-vectorized. grid (total4/256, nconv)
__global__ __launch_bounds__(256) void bn_apply2(
    Ptr6 Zs, PtrM6 Ss, Ptr6 Rs, const float* __restrict__ scale,
    const float* __restrict__ shift, int Cout, int total4, int mode)
{
    const int gix = blockIdx.y;
    const int i4  = blockIdx.x * 256 + threadIdx.x;
    if (i4 >= total4) return;
    const size_t base = (size_t)i4 * 4;
    const int d = (int)((base / NN) % (size_t)Cout);   // 4 elems share one d
    const float sc = scale[gix * Cout + d];
    const float sh = shift[gix * Cout + d];
    const float4 z = *(const float4*)(Zs.p[gix] + base);
    float4 o;
    o.x = (fmaf(sc, z.x, sh) >= 1.f) ? 1.f : 0.f;
    o.y = (fmaf(sc, z.y, sh) >= 1.f) ? 1.f : 0.f;
    o.z = (fmaf(sc, z.z, sh) >= 1.f) ? 1.f : 0.f;
    o.w = (fmaf(sc, z.w, sh) >= 1.f) ? 1.f : 0.f;
    if (mode == 1) {
        const float4 r = *(const float4*)(Rs.p[gix] + base);
        o.x += r.x; o.y += r.y; o.z += r.z; o.w += r.w;
    }
    *(float4*)(Ss.p[gix] + base) = o;
}

// ---------------------------------------------------------------------------
// Attention body (exact bit-packed popcount) — identical math to rounds 0-7.
// ---------------------------------------------------------------------------
__device__ __forceinline__ void attention_body(
    const float* __restrict__ Q, const float* __restrict__ K,
    const float* __restrict__ V, const float* __restrict__ P,
    float* __restrict__ O, int m, int h, int t,
    unsigned int* qb, unsigned int* kb, unsigned int* vb, float* Pl)
{
    if (P) { for (int i = t; i < 841; i += 256) Pl[i] = P[i]; }
    if (t < 196) {
        unsigned int q = 0, k = 0, v = 0;
        size_t base = (size_t)m * CC * NN + (size_t)h * 16 * NN + t;
        #pragma unroll
        for (int dd = 0; dd < 16; ++dd) {
            size_t off = base + (size_t)dd * NN;
            if (Q[off] > 0.5f) q |= (1u << dd);
            if (K[off] > 0.5f) k |= (1u << dd);
            if (V[off] > 0.5f) v |= (1u << dd);
        }
        qb[t] = q; kb[t] = k; vb[t] = v;
    }
    __syncthreads();

    if (t < 196) {
        int acc[16] = {0};
        const int ni = t / 14, nj = t - ni * 14;
        const unsigned int qr = qb[t];
        if (P) {
            for (int mm = 0; mm < 196; ++mm) {
                int a = __popc(qr & kb[mm]);
                int mi = mm / 14, mj = mm - mi * 14;
                float sv = (float)a + Pl[(ni - mi + 14) * 29 + (nj - mj + 14)];
                if (sv >= 1.f) {
                    unsigned int vv = vb[mm];
                    #pragma unroll
                    for (int dd = 0; dd < 16; ++dd)
                        acc[dd] += (vv >> dd) & 1;
                }
            }
        } else {
            for (int mm = 0; mm < 196; ++mm) {
                int a = __popc(qr & kb[mm]);
                if (a) {
                    unsigned int vv = vb[mm];
                    #pragma unroll
                    for (int dd = 0; dd < 16; ++dd)
                        acc[dd] += ((vv >> dd) & 1) ? a : 0;
                }
            }
        }
        size_t base = (size_t)m * CC * NN + (size_t)h * 16 * NN + t;
        #pragma unroll
        for (int dd = 0; dd < 16; ++dd)
            O[base + (size_t)dd * NN] = (acc[dd] >= 2) ? 1.f : 0.f;  // 0.25*acc >= 0.5
    }
}

// Both attention branches in one launch (validated round 7): z=0 x-branch,
// z=1 y-branch (with rpb). grid (32, 16, 2).
__global__ __launch_bounds__(256) void attention_k2(
    const float* __restrict__ Q0, const float* __restrict__ K0,
    const float* __restrict__ V0, float* __restrict__ O0,
    const float* __restrict__ Q1, const float* __restrict__ K1,
    const float* __restrict__ V1, float* __restrict__ O1,
    const float* __restrict__ P)
{
    __shared__ unsigned int qb[196], kb[196], vb[196];
    __shared__ float Pl[841];
    const int m = blockIdx.x, h = blockIdx.y, t = threadIdx.x;
    if (blockIdx.z == 0)
        attention_body(Q0, K0, V0, nullptr, O0, m, h, t, qb, kb, vb, Pl);
    else
        attention_body(Q1, K1, V1, P,       O1, m, h, t, qb, kb, vb, Pl);
}

extern "C" void kernel_launch(void* const* d_in, const int* in_sizes, int n_in,
                              void* d_out, int out_size, void* d_ws, size_t ws_size,
                              hipStream_t stream)
{
    const float* x     = (const float*)d_in[0];
    const float* y     = (const float*)d_in[1];
    const float* av_w  = (const float*)d_in[2];
    const float* av_g  = (const float*)d_in[3];
    const float* av_b  = (const float*)d_in[4];
    const float* va_w  = (const float*)d_in[5];
    const float* va_g  = (const float*)d_in[6];
    const float* va_b  = (const float*)d_in[7];
    const float* P_rpb = (const float*)d_in[8];
    const float* fc1_w = (const float*)d_in[9];
    const float* fc1_b = (const float*)d_in[10];
    const float* fc2_w = (const float*)d_in[11];
    const float* fc2_b = (const float*)d_in[12];
    const float* m1_w  = (const float*)d_in[13];
    const float* m1_b  = (const float*)d_in[14];
    const float* m1_g  = (const float*)d_in[15];
    const float* m1_bb = (const float*)d_in[16];
    const float* m2_w  = (const float*)d_in[17];
    const float* m2_b  = (const float*)d_in[18];
    const float* m2_g  = (const float*)d_in[19];
    const float* m2_bb = (const float*)d_in[20];
    float* out = (float*)d_out;

    float* ws    = (float*)d_ws;
    float* A     = ws;               // 6 * SLAB
    float* Bf    = A  + 6 * SLAB;    // 2 * SLAB
    float* Cf    = Bf + 2 * SLAB;    // 2 * SLAB
    float* scale = Cf + 2 * SLAB;    // 6 * 1024
    float* shift = scale + 6 * 1024;

    const size_t CC2 = (size_t)CC * CC;
    const int apply256  = (int)(SLAB / 4 / 256);     // 1568
    const int apply1024 = (int)(SLAB1K / 4 / 256);   // 6272

    // ---- Stage A: 6 first-layer convs (batched) -> A slabs --------------
    GArgs ga{};
    {
        const float* Wl[6] = { av_w, av_w + CC2, av_w + 2*CC2, va_w, va_w + CC2, va_w + 2*CC2 };
        const float* Il[6] = { x, y, y, y, x, x };
        for (int i = 0; i < 6; ++i)
            ga.a[i] = GArg{ Wl[i], Il[i], nullptr, nullptr, nullptr, nullptr, A + i*SLAB };
    }
    gemm4<<<dim3(CC/128, NJ/64, 6), 256, 0, stream>>>(ga, CC, CC, 0);

    Ptr6 Zs{}, gs{}, bs{}, Rs{}; PtrM6 Ss{};
    {
        const float* gl[6] = { av_g, av_g + CC, av_g + 2*CC, va_g, va_g + CC, va_g + 2*CC };
        const float* bl[6] = { av_b, av_b + CC, av_b + 2*CC, va_b, va_b + CC, va_b + 2*CC };
        for (int i = 0; i < 6; ++i) {
            Zs.p[i] = A + i*SLAB; Ss.p[i] = A + i*SLAB; gs.p[i] = gl[i]; bs.p[i] = bl[i];
        }
    }
    bn_stats<<<dim3(CC, 6), 256, 0, stream>>>(Zs, gs, bs, CC, scale, shift);
    bn_apply2<<<dim3(apply256, 6), 256, 0, stream>>>(Zs, Ss, Rs, scale, shift, CC, (int)(SLAB/4), 0);

    // ---- Stage B: both attentions, one launch ---------------------------
    attention_k2<<<dim3(TBB, 16, 2), 256, 0, stream>>>(
        A, A + SLAB, A + 2*SLAB, Bf,
        A + 3*SLAB, A + 4*SLAB, A + 5*SLAB, Bf + SLAB, P_rpb);

    // ---- Stage C: W3 conv (batched x2) + BN + LIF + residual -> x1,y1 ---
    GArgs gc{};
    gc.a[0] = GArg{ av_w + 3*CC2, Bf,        nullptr, nullptr, nullptr, nullptr, Cf };
    gc.a[1] = GArg{ va_w + 3*CC2, Bf + SLAB, nullptr, nullptr, nullptr, nullptr, Cf + SLAB };
    gemm4<<<dim3(CC/128, NJ/64, 2), 256, 0, stream>>>(gc, CC, CC, 0);
    Zs.p[0] = Cf; Zs.p[1] = Cf + SLAB;
    gs.p[0] = av_g + 3*CC; gs.p[1] = va_g + 3*CC;
    bs.p[0] = av_b + 3*CC; bs.p[1] = va_b + 3*CC;
    Rs.p[0] = x; Rs.p[1] = y;
    Ss.p[0] = A; Ss.p[1] = A + SLAB;          // x1, y1
    bn_stats<<<dim3(CC, 2), 256, 0, stream>>>(Zs, gs, bs, CC, scale, shift);
    bn_apply2<<<dim3(apply256, 2), 256, 0, stream>>>(Zs, Ss, Rs, scale, shift, CC, (int)(SLAB/4), 1);

    // ---- fc1@x1 + fc2@y1 + biases, fused LIF -> cur (Bf+SLAB) ----------
    GArgs gf{};
    gf.a[0] = GArg{ fc1_w, A, fc2_w, A + SLAB, fc1_b, fc2_b, Bf + SLAB };
    gemm4<<<dim3(CC/128, NJ/64, 1), 256, 0, stream>>>(gf, CC, CC, 1);

    // ---- m1: (1024x256) @ cur + BN + LIF -> h in A ---------------------
    GArgs g1{};
    g1.a[0] = GArg{ m1_w, Bf + SLAB, nullptr, nullptr, m1_b, nullptr, A };
    gemm4<<<dim3(HD/128, NJ/64, 1), 256, 0, stream>>>(g1, HD, CC, 0);
    Zs.p[0] = A; Ss.p[0] = A; gs.p[0] = m1_g; bs.p[0] = m1_bb;
    bn_stats<<<dim3(HD, 1), 256, 0, stream>>>(Zs, gs, bs, HD, scale, shift);
    bn_apply2<<<dim3(apply1024, 1), 256, 0, stream>>>(Zs, Ss, Rs, scale, shift, HD, (int)(SLAB1K/4), 0);

    // ---- m2: (256x1024) @ h + BN + LIF + (cur +) -> out ----------------
    GArgs g2{};
    g2.a[0] = GArg{ m2_w, A, nullptr, nullptr, m2_b, nullptr, Cf };
    gemm4<<<dim3(CC/128, NJ/64, 1), 256, 0, stream>>>(g2, CC, HD, 0);
    Zs.p[0] = Cf; gs.p[0] = m2_g; bs.p[0] = m2_bb;
    Rs.p[0] = Bf + SLAB;                      // cur
    Ss.p[0] = out;                            // out = cur + o  (fused)
    bn_stats<<<dim3(CC, 1), 256, 0, stream>>>(Zs, gs, bs, CC, scale, shift);
    bn_apply2<<<dim3(apply256, 1), 256, 0, stream>>>(Zs, Ss, Rs, scale, shift, CC, (int)(SLAB/4), 1);
}

// Round 9
// 553.954 us; speedup vs baseline: 5.4435x; 1.1959x over previous
//
#include <hip/hip_runtime.h>
#include <math.h>

#define TBB 32
#define CC  256
#define NN  196
#define NJ  (TBB * NN)            // 6272
#define HD  1024
#define SLAB   ((size_t)TBB * CC * NN)   // 1,605,632
#define SLAB1K ((size_t)TBB * HD * NN)   // 6,422,528

struct Ptr6  { const float* p[6]; };
struct PtrM6 { float*       p[6]; };

struct GArg {
    const float* W;  const float* In;
    const float* W2; const float* In2;
    const float* bias; const float* bias2;
    float* Z;
};
struct GArgs { GArg a[6]; };

struct UArg {
    const float* W; const unsigned char* In; const float* bias; float* Z;
};
struct UArgs { UArg a[2]; };

// async global->LDS; LDS dest = wave-uniform base + lane*size
__device__ __forceinline__ void async_copy16(const float* gsrc, float* ldst)
{
    typedef __attribute__((address_space(1))) void GV;
    typedef __attribute__((address_space(3))) void LV;
    __builtin_amdgcn_global_load_lds((GV*)const_cast<float*>(gsrc), (LV*)ldst,
                                     16, 0, 0);
}
__device__ __forceinline__ void async_copy4(const unsigned char* gsrc, unsigned char* ldst)
{
    typedef __attribute__((address_space(1))) void GV;
    typedef __attribute__((address_space(3))) void LV;
    __builtin_amdgcn_global_load_lds((GV*)const_cast<unsigned char*>(gsrc), (LV*)ldst,
                                     4, 0, 0);
}

// ---------------------------------------------------------------------------
// fp32 GEMM — EXACT round-1 proven kernel (100 us stage A, absmax 0.0), plus
// a mode-2 epilogue (u8 spike out). Used for stage A (fp32 inputs) and fc.
// mode 0: f32 z (+bias). mode 1: f32 spike. mode 2: u8 spike.
// ---------------------------------------------------------------------------
__global__ __launch_bounds__(256) void gemm2(GArgs ga, int Cout, int Cin, int mode)
{
    __shared__ __align__(16) float As[2][16][68];
    __shared__ __align__(16) float Bs[2][16][64];

    const GArg g = ga.a[blockIdx.z];
    const int t  = threadIdx.x;
    const int tx = t & 15, ty = t >> 4;
    const int d0 = blockIdx.x * 64;
    const int j0 = blockIdx.y * 64;
    const int lane = t & 63, wave = t >> 6;

    const int wrow = t >> 2;
    const int wk   = (t & 3) * 4;

    const int brow = wave * 4 + (lane >> 4);
    const int bj   = j0 + (lane & 15) * 4;
    const int bm   = bj / NN;
    const int bn   = bj - bm * NN;
    float* bdst0 = &Bs[0][wave * 4][0];
    float* bdst1 = &Bs[1][wave * 4][0];

    float acc[4][4] = {{0.f}};
    float4 wreg;

    for (int pass = 0; pass < 2; ++pass) {
        const float* Wp = pass ? g.W2 : g.W;
        const float* Ip = pass ? g.In2 : g.In;
        if (Wp == nullptr) break;
        const int nkt = Cin >> 4;
        const size_t wbase = (size_t)(d0 + wrow) * Cin + wk;
        const size_t bbase = (size_t)bm * Cin * NN + bn;

        async_copy16(Ip + bbase + (size_t)brow * NN, bdst0);
        wreg = *(const float4*)(Wp + wbase);
        As[0][wk + 0][wrow] = wreg.x;
        As[0][wk + 1][wrow] = wreg.y;
        As[0][wk + 2][wrow] = wreg.z;
        As[0][wk + 3][wrow] = wreg.w;
        __syncthreads();

        for (int kt = 0; kt < nkt; ++kt) {
            const int  cur  = kt & 1;
            const int  nxt  = cur ^ 1;
            const bool more = (kt + 1) < nkt;
            if (more) {
                const int k0n = (kt + 1) << 4;
                async_copy16(Ip + bbase + (size_t)(k0n + brow) * NN,
                             nxt ? bdst1 : bdst0);
                wreg = *(const float4*)(Wp + wbase + k0n);
            }
            #pragma unroll
            for (int kk = 0; kk < 16; ++kk) {
                float4 a4 = *(const float4*)(&As[cur][kk][ty * 4]);
                float4 b4 = *(const float4*)(&Bs[cur][kk][tx * 4]);
                float ar[4] = {a4.x, a4.y, a4.z, a4.w};
                float br[4] = {b4.x, b4.y, b4.z, b4.w};
                #pragma unroll
                for (int i = 0; i < 4; ++i)
                    #pragma unroll
                    for (int jj = 0; jj < 4; ++jj)
                        acc[i][jj] = fmaf(ar[i], br[jj], acc[i][jj]);
            }
            if (more) {
                As[nxt][wk + 0][wrow] = wreg.x;
                As[nxt][wk + 1][wrow] = wreg.y;
                As[nxt][wk + 2][wrow] = wreg.z;
                As[nxt][wk + 3][wrow] = wreg.w;
            }
            __syncthreads();
        }
    }

    #pragma unroll
    for (int i = 0; i < 4; ++i) {
        int d = d0 + ty * 4 + i;
        float bv = 0.f;
        if (g.bias)  bv += g.bias[d];
        if (g.bias2) bv += g.bias2[d];
        #pragma unroll
        for (int jj = 0; jj < 4; ++jj) {
            int j = j0 + tx * 4 + jj;
            int m = j / NN;
            int n = j - m * NN;
            float v = acc[i][jj] + bv;
            if (mode == 2) {
                ((unsigned char*)g.Z)[(size_t)(m * Cout + d) * NN + n] =
                    (v >= 1.f) ? (unsigned char)1 : (unsigned char)0;
            } else {
                g.Z[(size_t)(m * Cout + d) * NN + n] =
                    (mode == 1) ? ((v >= 1.f) ? 1.f : 0.f) : v;
            }
        }
    }
}

// ---------------------------------------------------------------------------
// u8-spike GEMM: Z[m,d,n] = sum_c W[d,c] * S[m,c,n], S in {0,1} stored u8.
// 32(d) x 128(j) tile, 256 threads, 2x8 micro, K-tile 16, double-buffered.
// B staged u8 via global_load_lds size=4 (4 j's per lane, contiguous: 196%4==0,
// m-boundaries are 4-aligned). A staged fp32 transposed (threads t<128).
// Per kk: ds_read_b64(A, broadcast) + ds_read_b64(B, conflict-free) +
// 8x v_cvt_f32_ubyte + 16 FMA -> LDS demand ~= VALU demand (fp32 gemm was 3x
// oversubscribed on LDS). u8->f32 conversion exact; FMA chain k-ascending ->
// BIT-IDENTICAL z to the round-1 kernel. Writes f32 z (+bias).
// ---------------------------------------------------------------------------
__global__ __launch_bounds__(256) void gemm_u8(UArgs ua, int Cout, int Cin)
{
    __shared__ __align__(16) float         As[2][16][36];
    __shared__ __align__(8)  unsigned char Bs[2][16][128];

    const UArg g = ua.a[blockIdx.z];
    const int t  = threadIdx.x;
    const int tx = t & 15;           // j-octet 0..15
    const int ty = t >> 4;           // d-pair 0..15
    const int d0 = blockIdx.x * 32;
    const int j0 = blockIdx.y * 128;
    const int lane = t & 63, wave = t >> 6;

    // B staging: two size-4 asyncs per wave per K-tile (rows 2w..2w+1, 8+2w..)
    const int brow = 2 * wave + (lane >> 5);       // source K-row within half
    const int bj   = j0 + (lane & 31) * 4;
    const int bm   = bj / NN;
    const int bn   = bj - bm * NN;
    const size_t bbase = (size_t)bm * Cin * NN + bn;

    // A staging (t < 128): thread covers W row (t&127)>>2, float4 at K off wk
    const int wrow = (t & 127) >> 2;               // 0..31
    const int wk   = (t & 3) * 4;
    const size_t wbase = (size_t)(d0 + wrow) * Cin + wk;

    float acc[2][8] = {{0.f}};
    float4 wreg;
    const int nkt = Cin >> 4;

    // prologue: K-tile 0 into buffer 0
    async_copy4(g.In + bbase + (size_t)brow * NN,       &Bs[0][2 * wave][0]);
    async_copy4(g.In + bbase + (size_t)(8 + brow) * NN, &Bs[0][8 + 2 * wave][0]);
    if (t < 128) {
        wreg = *(const float4*)(g.W + wbase);
        As[0][wk + 0][wrow] = wreg.x;
        As[0][wk + 1][wrow] = wreg.y;
        As[0][wk + 2][wrow] = wreg.z;
        As[0][wk + 3][wrow] = wreg.w;
    }
    __syncthreads();

    for (int kt = 0; kt < nkt; ++kt) {
        const int  cur  = kt & 1;
        const int  nxt  = cur ^ 1;
        const bool more = (kt + 1) < nkt;
        if (more) {
            const int k0n = (kt + 1) << 4;
            async_copy4(g.In + bbase + (size_t)(k0n + brow) * NN,
                        &Bs[nxt][2 * wave][0]);
            async_copy4(g.In + bbase + (size_t)(k0n + 8 + brow) * NN,
                        &Bs[nxt][8 + 2 * wave][0]);
            if (t < 128) wreg = *(const float4*)(g.W + wbase + k0n);
        }
        #pragma unroll
        for (int kk = 0; kk < 16; ++kk) {
            const float2 a2 = *(const float2*)(&As[cur][kk][ty * 2]);
            const uint2  bv = *(const uint2*)(&Bs[cur][kk][tx * 8]);
            float br[8];
            br[0] = (float)( bv.x        & 0xFF);
            br[1] = (float)((bv.x >>  8) & 0xFF);
            br[2] = (float)((bv.x >> 16) & 0xFF);
            br[3] = (float)( bv.x >> 24        );
            br[4] = (float)( bv.y        & 0xFF);
            br[5] = (float)((bv.y >>  8) & 0xFF);
            br[6] = (float)((bv.y >> 16) & 0xFF);
            br[7] = (float)( bv.y >> 24        );
            #pragma unroll
            for (int i = 0; i < 2; ++i) {
                const float a = i ? a2.y : a2.x;
                #pragma unroll
                for (int jj = 0; jj < 8; ++jj)
                    acc[i][jj] = fmaf(a, br[jj], acc[i][jj]);
            }
        }
        if (more && t < 128) {
            As[nxt][wk + 0][wrow] = wreg.x;
            As[nxt][wk + 1][wrow] = wreg.y;
            As[nxt][wk + 2][wrow] = wreg.z;
            As[nxt][wk + 3][wrow] = wreg.w;
        }
        __syncthreads();
    }

    // epilogue: two float4 stores per d (8-j chunk may straddle an m-boundary
    // only at 4-granularity, so each 4-chunk computes its own m,n)
    const int jb = j0 + tx * 8;
    #pragma unroll
    for (int i = 0; i < 2; ++i) {
        const int d = d0 + ty * 2 + i;
        const float bv = g.bias ? g.bias[d] : 0.f;
        #pragma unroll
        for (int h = 0; h < 2; ++h) {
            const int j = jb + h * 4;
            const int m = j / NN;
            const int n = j - m * NN;
            float4 o;
            o.x = acc[i][h * 4 + 0] + bv;
            o.y = acc[i][h * 4 + 1] + bv;
            o.z = acc[i][h * 4 + 2] + bv;
            o.w = acc[i][h * 4 + 3] + bv;
            *(float4*)(g.Z + (size_t)(m * Cout + d) * NN + n) = o;
        }
    }
}

// ---------------------------------------------------------------------------
// BN stats: per channel d over (m,n), fp64 accumulation. grid (Cout, nconv)
// ---------------------------------------------------------------------------
__global__ __launch_bounds__(256) void bn_stats(
    Ptr6 Zs, Ptr6 gs, Ptr6 bs, int Cout,
    float* __restrict__ scale, float* __restrict__ shift)
{
    const int d = blockIdx.x, g = blockIdx.y, t = threadIdx.x;
    const float* Z = Zs.p[g];
    double s = 0.0, s2 = 0.0;
    for (int i = t; i < NJ; i += 256) {
        int m = i / NN, n = i - m * NN;
        double v = (double)Z[(size_t)(m * Cout + d) * NN + n];
        s += v; s2 += v * v;
    }
    __shared__ double sh[256], sh2[256];
    sh[t] = s; sh2[t] = s2;
    __syncthreads();
    for (int off = 128; off > 0; off >>= 1) {
        if (t < off) { sh[t] += sh[t + off]; sh2[t] += sh2[t + off]; }
        __syncthreads();
    }
    if (t == 0) {
        double mu  = sh[0] / (double)NJ;
        double var = sh2[0] / (double)NJ - mu * mu;
        double a   = (double)gs.p[g][d] / sqrt(var + 1e-5);
        scale[g * Cout + d] = (float)a;
        shift[g * Cout + d] = (float)((double)bs.p[g][d] - mu * a);
    }
}

// spike = (scale[d]*z + shift[d] >= 1)
// mode 0: f32 spike out. mode 1: u8 spike out (Ss cast).
// mode 2: f32 out = spike + f32 residual. mode 3: f32 out = spike + u8 residual.
__global__ __launch_bounds__(256) void bn_apply2(
    Ptr6 Zs, PtrM6 Ss, Ptr6 Rs, const float* __restrict__ scale,
    const float* __restrict__ shift, int Cout, int total4, int mode)
{
    const int gix = blockIdx.y;
    const int i4  = blockIdx.x * 256 + threadIdx.x;
    if (i4 >= total4) return;
    const size_t base = (size_t)i4 * 4;
    const int d = (int)((base / NN) % (size_t)Cout);
    const float sc = scale[gix * Cout + d];
    const float sh = shift[gix * Cout + d];
    const float4 z = *(const float4*)(Zs.p[gix] + base);
    float4 o;
    o.x = (fmaf(sc, z.x, sh) >= 1.f) ? 1.f : 0.f;
    o.y = (fmaf(sc, z.y, sh) >= 1.f) ? 1.f : 0.f;
    o.z = (fmaf(sc, z.z, sh) >= 1.f) ? 1.f : 0.f;
    o.w = (fmaf(sc, z.w, sh) >= 1.f) ? 1.f : 0.f;
    if (mode == 1) {
        uchar4 u;
        u.x = (unsigned char)o.x; u.y = (unsigned char)o.y;
        u.z = (unsigned char)o.z; u.w = (unsigned char)o.w;
        *(uchar4*)((unsigned char*)Ss.p[gix] + base) = u;
        return;
    }
    if (mode == 2) {
        const float4 r = *(const float4*)(Rs.p[gix] + base);
        o.x += r.x; o.y += r.y; o.z += r.z; o.w += r.w;
    } else if (mode == 3) {
        const uchar4 r = *(const uchar4*)((const unsigned char*)Rs.p[gix] + base);
        o.x += (float)r.x; o.y += (float)r.y; o.z += (float)r.z; o.w += (float)r.w;
    }
    *(float4*)(Ss.p[gix] + base) = o;
}

// ---------------------------------------------------------------------------
// Attention (exact bit-packed popcount), u8 spike I/O. Math identical.
// ---------------------------------------------------------------------------
__device__ __forceinline__ void attention_body(
    const unsigned char* __restrict__ Q, const unsigned char* __restrict__ K,
    const unsigned char* __restrict__ V, const float* __restrict__ P,
    unsigned char* __restrict__ O, int m, int h, int t,
    unsigned int* qb, unsigned int* kb, unsigned int* vb, float* Pl)
{
    if (P) { for (int i = t; i < 841; i += 256) Pl[i] = P[i]; }
    if (t < 196) {
        unsigned int q = 0, k = 0, v = 0;
        size_t base = (size_t)m * CC * NN + (size_t)h * 16 * NN + t;
        #pragma unroll
        for (int dd = 0; dd < 16; ++dd) {
            size_t off = base + (size_t)dd * NN;
            if (Q[off]) q |= (1u << dd);
            if (K[off]) k |= (1u << dd);
            if (V[off]) v |= (1u << dd);
        }
        qb[t] = q; kb[t] = k; vb[t] = v;
    }
    __syncthreads();

    if (t < 196) {
        int acc[16] = {0};
        const int ni = t / 14, nj = t - ni * 14;
        const unsigned int qr = qb[t];
        if (P) {
            for (int mm = 0; mm < 196; ++mm) {
                int a = __popc(qr & kb[mm]);
                int mi = mm / 14, mj = mm - mi * 14;
                float sv = (float)a + Pl[(ni - mi + 14) * 29 + (nj - mj + 14)];
                if (sv >= 1.f) {
                    unsigned int vv = vb[mm];
                    #pragma unroll
                    for (int dd = 0; dd < 16; ++dd)
                        acc[dd] += (vv >> dd) & 1;
                }
            }
        } else {
            for (int mm = 0; mm < 196; ++mm) {
                int a = __popc(qr & kb[mm]);
                if (a) {
                    unsigned int vv = vb[mm];
                    #pragma unroll
                    for (int dd = 0; dd < 16; ++dd)
                        acc[dd] += ((vv >> dd) & 1) ? a : 0;
                }
            }
        }
        size_t base = (size_t)m * CC * NN + (size_t)h * 16 * NN + t;
        #pragma unroll
        for (int dd = 0; dd < 16; ++dd)
            O[base + (size_t)dd * NN] = (acc[dd] >= 2) ? 1 : 0;  // 0.25*acc >= 0.5
    }
}

__global__ __launch_bounds__(256) void attention_k2(
    const unsigned char* __restrict__ Q0, const unsigned char* __restrict__ K0,
    const unsigned char* __restrict__ V0, unsigned char* __restrict__ O0,
    const unsigned char* __restrict__ Q1, const unsigned char* __restrict__ K1,
    const unsigned char* __restrict__ V1, unsigned char* __restrict__ O1,
    const float* __restrict__ P)
{
    __shared__ unsigned int qb[196], kb[196], vb[196];
    __shared__ float Pl[841];
    const int m = blockIdx.x, h = blockIdx.y, t = threadIdx.x;
    if (blockIdx.z == 0)
        attention_body(Q0, K0, V0, nullptr, O0, m, h, t, qb, kb, vb, Pl);
    else
        attention_body(Q1, K1, V1, P,       O1, m, h, t, qb, kb, vb, Pl);
}

extern "C" void kernel_launch(void* const* d_in, const int* in_sizes, int n_in,
                              void* d_out, int out_size, void* d_ws, size_t ws_size,
                              hipStream_t stream)
{
    const float* x     = (const float*)d_in[0];
    const float* y     = (const float*)d_in[1];
    const float* av_w  = (const float*)d_in[2];
    const float* av_g  = (const float*)d_in[3];
    const float* av_b  = (const float*)d_in[4];
    const float* va_w  = (const float*)d_in[5];
    const float* va_g  = (const float*)d_in[6];
    const float* va_b  = (const float*)d_in[7];
    const float* P_rpb = (const float*)d_in[8];
    const float* fc1_w = (const float*)d_in[9];
    const float* fc1_b = (const float*)d_in[10];
    const float* fc2_w = (const float*)d_in[11];
    const float* fc2_b = (const float*)d_in[12];
    const float* m1_w  = (const float*)d_in[13];
    const float* m1_b  = (const float*)d_in[14];
    const float* m1_g  = (const float*)d_in[15];
    const float* m1_bb = (const float*)d_in[16];
    const float* m2_w  = (const float*)d_in[17];
    const float* m2_b  = (const float*)d_in[18];
    const float* m2_g  = (const float*)d_in[19];
    const float* m2_bb = (const float*)d_in[20];
    float* out = (float*)d_out;

    float* ws    = (float*)d_ws;
    float* A     = ws;               // 6 * SLAB f32
    float* Bf    = A  + 6 * SLAB;    // 2 * SLAB f32
    float* Cf    = Bf + 2 * SLAB;    // 2 * SLAB f32
    float* scale = Cf + 2 * SLAB;    // 6 * 1024
    float* shift = scale + 6 * 1024;

    // u8 regions (SLAB bytes each), overlaid on dead f32 regions per stage:
    unsigned char* Qu  = (unsigned char*)Bf;        // 6 spike slabs (9.6MB < 12.8MB)
    unsigned char* Ou  = (unsigned char*)Cf;        // 2 o-spike slabs (3.2MB)
    unsigned char* cur = (unsigned char*)Bf;        // cur u8 (QKV dead by then)
    unsigned char* Hu  = (unsigned char*)(Cf + SLAB); // h u8 (6.4MB region)

    const size_t CC2 = (size_t)CC * CC;
    const int apply256  = (int)(SLAB / 4 / 256);     // 1568
    const int apply1024 = (int)(SLAB1K / 4 / 256);   // 6272

    // ---- Stage A: 6 first-layer convs (fp32, batched) -> A slabs ---------
    GArgs ga{};
    {
        const float* Wl[6] = { av_w, av_w + CC2, av_w + 2*CC2, va_w, va_w + CC2, va_w + 2*CC2 };
        const float* Il[6] = { x, y, y, y, x, x };
        for (int i = 0; i < 6; ++i)
            ga.a[i] = GArg{ Wl[i], Il[i], nullptr, nullptr, nullptr, nullptr, A + i*SLAB };
    }
    gemm2<<<dim3(CC/64, NJ/64, 6), 256, 0, stream>>>(ga, CC, CC, 0);

    Ptr6 Zs{}, gs{}, bs{}, Rs{}; PtrM6 Ss{};
    {
        const float* gl[6] = { av_g, av_g + CC, av_g + 2*CC, va_g, va_g + CC, va_g + 2*CC };
        const float* bl[6] = { av_b, av_b + CC, av_b + 2*CC, va_b, va_b + CC, va_b + 2*CC };
        for (int i = 0; i < 6; ++i) {
            Zs.p[i] = A + i*SLAB;
            Ss.p[i] = (float*)(Qu + i*SLAB);   // u8 spike slabs
            gs.p[i] = gl[i]; bs.p[i] = bl[i];
        }
    }
    bn_stats<<<dim3(CC, 6), 256, 0, stream>>>(Zs, gs, bs, CC, scale, shift);
    bn_apply2<<<dim3(apply256, 6), 256, 0, stream>>>(Zs, Ss, Rs, scale, shift, CC, (int)(SLAB/4), 1);

    // ---- Stage B: both attentions, one launch (u8 I/O) -------------------
    attention_k2<<<dim3(TBB, 16, 2), 256, 0, stream>>>(
        Qu, Qu + SLAB, Qu + 2*SLAB, Ou,
        Qu + 3*SLAB, Qu + 4*SLAB, Qu + 5*SLAB, Ou + SLAB, P_rpb);

    // ---- Stage C: W3 conv via gemm_u8 -> z f32 in A[0], A[1] -------------
    {
        UArgs uc{};
        uc.a[0] = UArg{ av_w + 3*CC2, Ou,        nullptr, A };
        uc.a[1] = UArg{ va_w + 3*CC2, Ou + SLAB, nullptr, A + SLAB };
        gemm_u8<<<dim3(CC/32, NJ/128, 2), 256, 0, stream>>>(uc, CC, CC);
    }
    Zs.p[0] = A; Zs.p[1] = A + SLAB;
    gs.p[0] = av_g + 3*CC; gs.p[1] = va_g + 3*CC;
    bs.p[0] = av_b + 3*CC; bs.p[1] = va_b + 3*CC;
    Rs.p[0] = x; Rs.p[1] = y;
    Ss.p[0] = A + 2*SLAB; Ss.p[1] = A + 3*SLAB;     // x1, y1 (f32)
    bn_stats<<<dim3(CC, 2), 256, 0, stream>>>(Zs, gs, bs, CC, scale, shift);
    bn_apply2<<<dim3(apply256, 2), 256, 0, stream>>>(Zs, Ss, Rs, scale, shift, CC, (int)(SLAB/4), 2);

    // ---- fc1@x1 + fc2@y1 + biases, fused LIF -> cur (u8, Bf) -------------
    GArgs gf{};
    gf.a[0] = GArg{ fc1_w, A + 2*SLAB, fc2_w, A + 3*SLAB, fc1_b, fc2_b, (float*)cur };
    gemm2<<<dim3(CC/64, NJ/64, 1), 256, 0, stream>>>(gf, CC, CC, 2);

    // ---- m1 via gemm_u8: (1024x256) @ cur -> z f32 in A[0..4S) -----------
    {
        UArgs u1{};
        u1.a[0] = UArg{ m1_w, cur, m1_b, A };
        gemm_u8<<<dim3(HD/32, NJ/128, 1), 256, 0, stream>>>(u1, HD, CC);
    }
    Zs.p[0] = A; Ss.p[0] = (float*)Hu; gs.p[0] = m1_g; bs.p[0] = m1_bb;
    bn_stats<<<dim3(HD, 1), 256, 0, stream>>>(Zs, gs, bs, HD, scale, shift);
    bn_apply2<<<dim3(apply1024, 1), 256, 0, stream>>>(Zs, Ss, Rs, scale, shift, HD, (int)(SLAB1K/4), 1);

    // ---- m2 via gemm_u8: (256x1024) @ h -> z f32 in Bf+SLAB --------------
    {
        UArgs u2{};
        u2.a[0] = UArg{ m2_w, Hu, m2_b, Bf + SLAB };
        gemm_u8<<<dim3(CC/32, NJ/128, 1), 256, 0, stream>>>(u2, CC, HD);
    }
    Zs.p[0] = Bf + SLAB; gs.p[0] = m2_g; bs.p[0] = m2_bb;
    Rs.p[0] = (const float*)cur;           // u8 residual
    Ss.p[0] = out;                         // out = spike + cur (f32)
    bn_stats<<<dim3(CC, 1), 256, 0, stream>>>(Zs, gs, bs, CC, scale, shift);
    bn_apply2<<<dim3(apply256, 1), 256, 0, stream>>>(Zs, Ss, Rs, scale, shift, CC, (int)(SLAB/4), 3);
}